// Round 7
// baseline (611.094 us; speedup 1.0000x reference)
//
#include <hip/hip_runtime.h>
#include <hip/hip_bf16.h>
#include <math.h>

// Problem constants
#define N_ATOMS   50000
#define N_EDGES   800000
#define KDIM      192
#define BN_EPS    1e-5f

#define TILE_E     64
#define TPB        5                       // tiles per block (pass 1)
#define NTILES     (N_EDGES / TILE_E)      // 12500
#define GRID1      (NTILES / TPB)          // 2500
#define STAT_SLOTS 32
#define ZSTRIDE    200   // bf16 elems per FULL z row (fallback kernel LDS)
#define ZAST       136   // bf16 elems per 2-seg z row (main kernel: 128 + 8 pad)
#define SCAN_T     1024
#define SCAN_E     ((N_ATOMS + SCAN_T - 1) / SCAN_T)   // 49

typedef __attribute__((ext_vector_type(8))) __bf16 bf16x8;
typedef __attribute__((ext_vector_type(4))) float  f32x4;
typedef __attribute__((ext_vector_type(4))) unsigned short u16x4;
typedef __attribute__((ext_vector_type(8))) unsigned short u16x8;

__device__ __forceinline__ ushort f2bf(float f) {
    union { float f; unsigned u; } v; v.f = f;
    unsigned u = v.u;
    return (ushort)((u + 0x7FFFu + ((u >> 16) & 1u)) >> 16);
}
__device__ __forceinline__ float bf2f(unsigned hi16) {
    union { unsigned u; float f; } v; v.u = hi16 << 16; return v.f;
}
// BN + sigmoid*softplus message from packed (core | filter<<16) bf16 pair.
// rcp instead of full-precision divide (1 instr vs rcp+Newton; ~1ulp, fine
// at absmax 0.25).
__device__ __forceinline__ float msgf(unsigned pv, float sc_c, float sh_c,
                                      float sc_f, float sh_f) {
    float pc = fmaf(bf2f(pv & 0xFFFFu), sc_c, sh_c);
    float pf = fmaf(bf2f(pv >> 16),     sc_f, sh_f);
    float sp = fmaxf(pc, 0.f) + __logf(1.f + __expf(-fabsf(pc)));
    float sg = __builtin_amdgcn_rcpf(1.f + __expf(-pf));
    return sp * sg;
}

// ---------------------------------------------------------------------------
// Gather split (ATOM segments only, main kernel): issue (global->regs) /
// commit (bf16 convert -> LDS). 16 lanes read one 256B atom row contiguously.
// ---------------------------------------------------------------------------
__device__ __forceinline__ void gather_issue_a(
    const float* __restrict__ atom, const int* __restrict__ eidx,
    int tilebase, int tid, f32x4* v)
{
    const int er = tid >> 4, f4 = tid & 15;
#pragma unroll
    for (int it = 0; it < 8; ++it) {
        const int seg = it >> 2;                 // 0=dst, 1=src
        const int e   = (it & 3) * 16 + er;
        const float* srcp =
            atom + (size_t)eidx[2 * (tilebase + e) + (seg == 0 ? 1 : 0)] * 64;
        v[it] = *(const f32x4*)(srcp + f4 * 4);
    }
}

__device__ __forceinline__ void gather_commit_a(const f32x4* v, ushort* zl, int tid)
{
    const int er = tid >> 4, f4 = tid & 15;
#pragma unroll
    for (int it = 0; it < 8; ++it) {
        const int seg = it >> 2;
        const int e   = (it & 3) * 16 + er;
        u16x4 b;
        b.x = f2bf(v[it].x); b.y = f2bf(v[it].y);
        b.z = f2bf(v[it].z); b.w = f2bf(v[it].w);
        *(u16x4*)&zl[e * ZAST + seg * 64 + f4 * 4] = b;
    }
}

// Full-z gather helpers (fallback kernel only)
__device__ __forceinline__ void gather_issue(
    const float* __restrict__ atom, const float* __restrict__ edgef,
    const int* __restrict__ eidx, int tilebase, int tid, f32x4* v)
{
    const int er = tid >> 4, f4 = tid & 15;
#pragma unroll
    for (int it = 0; it < 12; ++it) {
        const int seg = it >> 2;
        const int e   = (it & 3) * 16 + er;
        const float* srcp;
        if (seg == 0)      srcp = atom  + (size_t)eidx[2 * (tilebase + e) + 1] * 64;
        else if (seg == 1) srcp = atom  + (size_t)eidx[2 * (tilebase + e)] * 64;
        else               srcp = edgef + (size_t)(tilebase + e) * 64;
        v[it] = *(const f32x4*)(srcp + f4 * 4);
    }
}

__device__ __forceinline__ void gather_commit(const f32x4* v, ushort* zl, int tid)
{
    const int er = tid >> 4, f4 = tid & 15;
#pragma unroll
    for (int it = 0; it < 12; ++it) {
        const int seg = it >> 2;
        const int e   = (it & 3) * 16 + er;
        u16x4 b;
        b.x = f2bf(v[it].x); b.y = f2bf(v[it].y);
        b.z = f2bf(v[it].z); b.w = f2bf(v[it].w);
        *(u16x4*)&zl[e * ZSTRIDE + seg * 64 + f4 * 4] = b;
    }
}

// ---------------------------------------------------------------------------
// Pass 1: round-6 structure + ef-direct (round-2 idea, UNFORCED this time):
// edge-feature A-fragments (ks=4,5) load directly from global in fragment
// layout (contiguous by edge id), shrinking LDS to 36.4KB -> 4 blocks/CU at
// natural VGPR (~116). NO __launch_bounds__ min-waves (round-2 spill lesson).
// Inline perml build: perml[i] = row_start[dst(e)] + rank[e] (round-6 win).
// One __syncthreads per tile: commit(t) | sync | issue(t+1) | MFMA(t)+store.
// ---------------------------------------------------------------------------
__global__ __launch_bounds__(256) void gemm_stats_store(
    const float* __restrict__ atom, const float* __restrict__ edgef,
    const ushort* __restrict__ Wb, const int* __restrict__ eidx,
    const unsigned* __restrict__ row_start, const unsigned* __restrict__ rank,
    float* __restrict__ stat_partial, unsigned* __restrict__ ws_pre,
    int do_store)
{
    __shared__ __align__(16) ushort zbuf[2][TILE_E * ZAST]; // 2x17.0KB
    __shared__ unsigned perml[TPB * TILE_E];                // 1.25KB
    const int tid  = threadIdx.x;
    const int lane = tid & 63, wave = tid >> 6;
    const int ch = wave >> 1, rp = wave & 1;
    const int row = lane & 15, quad = lane >> 4;

    const int t0 = blockIdx.x * TPB;
    if (do_store) {
        for (int i = tid; i < TPB * TILE_E; i += 256) {
            const int e = t0 * TILE_E + i;
            const int d = eidx[2 * e + 1];
            perml[i] = row_start[d] + rank[e];
        }
    }

    bf16x8 bfr[2][2][6];
#pragma unroll
    for (int m = 0; m < 2; ++m)
#pragma unroll
        for (int nt = 0; nt < 2; ++nt)
#pragma unroll
            for (int ks = 0; ks < 6; ++ks)
                bfr[m][nt][ks] = *(const bf16x8*)&Wb[
                    (size_t)(m * 64 + ch * 32 + nt * 16 + row) * KDIM + ks * 32 + quad * 8];

    float s[2][2] = {{0.f, 0.f}, {0.f, 0.f}};
    float q[2][2] = {{0.f, 0.f}, {0.f, 0.f}};

    f32x4 pre[8];
    gather_issue_a(atom, eidx, t0 * TILE_E, tid, pre);

    for (int tt = 0; tt < TPB; ++tt) {
        ushort* zl = zbuf[tt & 1];
        gather_commit_a(pre, zl, tid);
        __syncthreads();   // zl + perml visible; also protects buffer reuse
        if (tt + 1 < TPB)
            gather_issue_a(atom, eidx, (t0 + tt + 1) * TILE_E, tid, pre);

#pragma unroll
        for (int ett = 0; ett < 2; ++ett) {
            // direct edge-feature fragment loads (z cols 128..191)
            const size_t ebase =
                (size_t)((t0 + tt) * TILE_E + (2 * rp + ett) * 16 + row) * 64;
            f32x4 ef0 = *(const f32x4*)&edgef[ebase + quad * 8];
            f32x4 ef1 = *(const f32x4*)&edgef[ebase + quad * 8 + 4];
            f32x4 ef2 = *(const f32x4*)&edgef[ebase + 32 + quad * 8];
            f32x4 ef3 = *(const f32x4*)&edgef[ebase + 32 + quad * 8 + 4];

            const ushort* zb = zl + ((2 * rp + ett) * 16 + row) * ZAST;
            bf16x8 a[6];
#pragma unroll
            for (int ks = 0; ks < 4; ++ks)
                a[ks] = *(const bf16x8*)&zb[ks * 32 + quad * 8];
            {
                union { u16x8 u; bf16x8 b; } t4, t5;
#pragma unroll
                for (int j = 0; j < 4; ++j) {
                    t4.u[j]     = f2bf(ef0[j]);
                    t4.u[4 + j] = f2bf(ef1[j]);
                    t5.u[j]     = f2bf(ef2[j]);
                    t5.u[4 + j] = f2bf(ef3[j]);
                }
                a[4] = t4.b; a[5] = t5.b;
            }

            f32x4 acc[2][2];
#pragma unroll
            for (int m = 0; m < 2; ++m)
#pragma unroll
                for (int nt = 0; nt < 2; ++nt)
                    acc[m][nt] = (f32x4){0.f, 0.f, 0.f, 0.f};
#pragma unroll
            for (int ks = 0; ks < 6; ++ks)
#pragma unroll
                for (int m = 0; m < 2; ++m)
#pragma unroll
                    for (int nt = 0; nt < 2; ++nt)
                        acc[m][nt] = __builtin_amdgcn_mfma_f32_16x16x32_bf16(
                            a[ks], bfr[m][nt][ks], acc[m][nt], 0, 0, 0);
#pragma unroll
            for (int nt = 0; nt < 2; ++nt) {
                const int c = ch * 32 + nt * 16 + row;
#pragma unroll
                for (int r = 0; r < 4; ++r) {
                    float vc = acc[0][nt][r], vf = acc[1][nt][r];
                    s[0][nt] += vc; q[0][nt] += vc * vc;
                    s[1][nt] += vf; q[1][nt] += vf * vf;
                    if (do_store) {
                        const int eloc = (2 * rp + ett) * 16 + quad * 4 + r;
                        const unsigned pos = perml[tt * TILE_E + eloc];
                        unsigned pack = (unsigned)f2bf(vc) | ((unsigned)f2bf(vf) << 16);
                        ws_pre[(size_t)pos * 64 + c] = pack;  // plain store: L2 merges
                    }
                }
            }
        }
    }

    float* slot = stat_partial + (size_t)(blockIdx.x & (STAT_SLOTS - 1)) * 256;
#pragma unroll
    for (int m = 0; m < 2; ++m)
#pragma unroll
        for (int nt = 0; nt < 2; ++nt) {
            float sv = s[m][nt], qv = q[m][nt];
            sv += __shfl_xor(sv, 16, 64); sv += __shfl_xor(sv, 32, 64);
            qv += __shfl_xor(qv, 16, 64); qv += __shfl_xor(qv, 32, 64);
            if (lane < 16) {
                int c = ch * 32 + nt * 16 + lane;
                atomicAdd(slot + m * 128 + c, sv);
                atomicAdd(slot + m * 128 + 64 + c, qv);
            }
        }
}

// ---------------------------------------------------------------------------
// Fused setup: zero stat_partial + counts, convert weights to bf16.
// ---------------------------------------------------------------------------
__global__ __launch_bounds__(256) void setup_all(
    const float* __restrict__ Wc, const float* __restrict__ Wf,
    ushort* __restrict__ Wb, float* __restrict__ stat_partial,
    unsigned* __restrict__ counts)
{
    int i = blockIdx.x * 256 + threadIdx.x;       // 256 blocks -> 65536 threads
    if (i < 2 * 64 * KDIM) {
        float v = (i < 64 * KDIM) ? Wc[i] : Wf[i - 64 * KDIM];
        Wb[i] = f2bf(v);
    }
    if (i < STAT_SLOTS * 256) stat_partial[i] = 0.f;
    if (i < N_ATOMS) counts[i] = 0u;
}

// ---------------------------------------------------------------------------
// Fold BN into per-column scale/shift (1-block kernel).
// params: [0..63]=scale_c [64..127]=scale_f [128..191]=shift_c [192..255]=shift_f
// ---------------------------------------------------------------------------
__global__ void finalize_stats(const float* __restrict__ stat_partial,
                               const float* __restrict__ gc, const float* __restrict__ btc,
                               const float* __restrict__ gf, const float* __restrict__ btf,
                               float* __restrict__ params)
{
    int t = threadIdx.x;            // 0..127
    bool isf = t >= 64;
    int j = t & 63;
    float s = 0.f, q = 0.f;
    for (int slot = 0; slot < STAT_SLOTS; slot++) {
        const float* sp = stat_partial + (size_t)slot * 256 + (isf ? 128 : 0);
        s += sp[j];
        q += sp[64 + j];
    }
    float mean = s / (float)N_EDGES;
    float var  = q / (float)N_EDGES - mean * mean;
    float inv  = rsqrtf(var + BN_EPS);
    float gamma = isf ? gf[j] : gc[j];
    float beta  = isf ? btf[j] : btc[j];
    float scale = gamma * inv;
    float shift = beta - mean * scale;
    params[t]       = scale;
    params[128 + t] = shift;
}

// ---------------------------------------------------------------------------
// CSR-slot assignment:
//   hist_rank: rank[e] = atomicAdd(&counts[d],1)  (the histogram atomic's
//              return value IS the within-dst rank)
//   scan_one:  single-block exclusive scan of counts -> row_start (+sentinel).
//              Replaces scan_a + scan_b + init_row (one dispatch, no
//              cross-block ordering assumptions; ~5us for 50k elements).
// ---------------------------------------------------------------------------
__global__ __launch_bounds__(256) void hist_rank(const int* __restrict__ eidx,
                                                 unsigned* __restrict__ counts,
                                                 unsigned* __restrict__ rank)
{
    int e = blockIdx.x * 256 + threadIdx.x;          // 3125 blocks
    rank[e] = atomicAdd(&counts[eidx[2 * e + 1]], 1u);
}

__global__ __launch_bounds__(SCAN_T) void scan_one(
    const unsigned* __restrict__ counts, unsigned* __restrict__ row_start)
{
    __shared__ unsigned sh[SCAN_T];
    const int t = threadIdx.x;
    const int base = t * SCAN_E;

    unsigned sum = 0;
    for (int j = 0; j < SCAN_E; ++j) {
        int i = base + j;
        if (i < N_ATOMS) sum += counts[i];
    }
    sh[t] = sum;
    __syncthreads();
    for (int off = 1; off < SCAN_T; off <<= 1) {      // Hillis-Steele inclusive
        unsigned v = (t >= off) ? sh[t - off] : 0u;
        __syncthreads();
        sh[t] += v;
        __syncthreads();
    }
    unsigned run = (t > 0) ? sh[t - 1] : 0u;          // exclusive chunk prefix
    for (int j = 0; j < SCAN_E; ++j) {
        int i = base + j;
        if (i < N_ATOMS) {
            unsigned c = counts[i];
            row_start[i] = run;
            run += c;
        }
    }
    if (t == 0) row_start[N_ATOMS] = N_EDGES;         // sentinel
}

// ---------------------------------------------------------------------------
// Pass 3: streaming gather-reduce. ws_pre rows are in CSR order: each wave
// (one atom, lane = column) reads a CONTIGUOUS run of 256B rows. One plain
// store per atom; no atomics, no index indirection.
// ---------------------------------------------------------------------------
__global__ __launch_bounds__(256) void bn_act_reduce(
    const unsigned* __restrict__ ws_pre, const unsigned* __restrict__ row_start,
    const float* __restrict__ atom, const float* __restrict__ params,
    float* __restrict__ out)
{
    const int lane = threadIdx.x & 63;
    const int a    = blockIdx.x * 4 + (threadIdx.x >> 6);

    const float sc_c = params[lane],      sh_c = params[128 + lane];
    const float sc_f = params[64 + lane], sh_f = params[192 + lane];

    const unsigned jb = row_start[a];
    const unsigned n  = row_start[a + 1] - jb;
    const unsigned* base = ws_pre + (size_t)jb * 64 + lane;

    float acc = 0.f;
    unsigned k = 0;
    for (; k + 8 <= n; k += 8) {
        unsigned p[8];
#pragma unroll
        for (int u = 0; u < 8; ++u) p[u] = base[(size_t)(k + u) * 64];
#pragma unroll
        for (int u = 0; u < 8; ++u) acc += msgf(p[u], sc_c, sh_c, sc_f, sh_f);
    }
    for (; k < n; ++k) acc += msgf(base[(size_t)k * 64], sc_c, sh_c, sc_f, sh_f);

    out[(size_t)a * 64 + lane] = atom[(size_t)a * 64 + lane] + acc;
}

// ---------------------------------------------------------------------------
// Fallback path (ws too small): recompute GEMM + atomic scatter (no ws_pre).
// ---------------------------------------------------------------------------
__global__ __launch_bounds__(256) void copy_out(const f32x4* __restrict__ src,
                                                f32x4* __restrict__ dst)
{
    int i = blockIdx.x * blockDim.x + threadIdx.x;
    dst[i] = src[i];
}

__global__ __launch_bounds__(256) void apply_scatter_fb(
    const float* __restrict__ atom, const float* __restrict__ edgef,
    const ushort* __restrict__ Wb, const int* __restrict__ eidx,
    const float* __restrict__ params, float* __restrict__ out)
{
    __shared__ __align__(16) ushort zl[TILE_E * ZSTRIDE];
    const int tid  = threadIdx.x;
    const int lane = tid & 63, wave = tid >> 6;
    const int ch = wave >> 1, rp = wave & 1;
    const int row = lane & 15, quad = lane >> 4;

    bf16x8 bfr[2][2][6];
#pragma unroll
    for (int m = 0; m < 2; ++m)
#pragma unroll
        for (int nt = 0; nt < 2; ++nt)
#pragma unroll
            for (int ks = 0; ks < 6; ++ks)
                bfr[m][nt][ks] = *(const bf16x8*)&Wb[
                    (size_t)(m * 64 + ch * 32 + nt * 16 + row) * KDIM + ks * 32 + quad * 8];

    float scc[2], shc[2], scf[2], shf[2];
#pragma unroll
    for (int nt = 0; nt < 2; ++nt) {
        int c = ch * 32 + nt * 16 + row;
        scc[nt] = params[c];        shc[nt] = params[128 + c];
        scf[nt] = params[64 + c];   shf[nt] = params[192 + c];
    }

    const int t0 = blockIdx.x * TPB;
    for (int tt = 0; tt < TPB; ++tt) {
        const int tilebase = (t0 + tt) * TILE_E;
        f32x4 pre[12];
        gather_issue(atom, edgef, eidx, tilebase, tid, pre);
        __syncthreads();
        gather_commit(pre, zl, tid);
        __syncthreads();
#pragma unroll
        for (int ett = 0; ett < 2; ++ett) {
            const ushort* zb = zl + ((2 * rp + ett) * 16 + row) * ZSTRIDE;
            bf16x8 a[6];
#pragma unroll
            for (int ks = 0; ks < 6; ++ks)
                a[ks] = *(const bf16x8*)&zb[ks * 32 + quad * 8];
            f32x4 acc[2][2];
#pragma unroll
            for (int m = 0; m < 2; ++m)
#pragma unroll
                for (int nt = 0; nt < 2; ++nt)
                    acc[m][nt] = (f32x4){0.f, 0.f, 0.f, 0.f};
#pragma unroll
            for (int ks = 0; ks < 6; ++ks)
#pragma unroll
                for (int m = 0; m < 2; ++m)
#pragma unroll
                    for (int nt = 0; nt < 2; ++nt)
                        acc[m][nt] = __builtin_amdgcn_mfma_f32_16x16x32_bf16(
                            a[ks], bfr[m][nt][ks], acc[m][nt], 0, 0, 0);
#pragma unroll
            for (int nt = 0; nt < 2; ++nt) {
                int c = ch * 32 + nt * 16 + row;
#pragma unroll
                for (int r = 0; r < 4; ++r) {
                    float pc = fmaf(acc[0][nt][r], scc[nt], shc[nt]);
                    float pf = fmaf(acc[1][nt][r], scf[nt], shf[nt]);
                    float sp = fmaxf(pc, 0.f) + __logf(1.f + __expf(-fabsf(pc)));
                    float sg = 1.f / (1.f + __expf(-pf));
                    int eloc = (2 * rp + ett) * 16 + quad * 4 + r;
                    int d = eidx[2 * (tilebase + eloc) + 1];
                    atomicAdd(out + (size_t)d * 64 + c, sp * sg);
                }
            }
        }
    }
}

// ---------------------------------------------------------------------------
extern "C" void kernel_launch(void* const* d_in, const int* in_sizes, int n_in,
                              void* d_out, int out_size, void* d_ws, size_t ws_size,
                              hipStream_t stream)
{
    const float* atom  = (const float*)d_in[0];
    const float* edgef = (const float*)d_in[1];
    const float* Wf    = (const float*)d_in[2];
    const float* gf    = (const float*)d_in[4];
    const float* btf   = (const float*)d_in[5];
    const float* Wc    = (const float*)d_in[6];
    const float* gc    = (const float*)d_in[8];
    const float* btc   = (const float*)d_in[9];
    const int*   eidx  = (const int*)d_in[10];
    float* out = (float*)d_out;

    // workspace layout (ws_pre first keeps everything 16B-aligned)
    unsigned* ws_pre       = (unsigned*)d_ws;                          // N_EDGES*64
    float*    stat_partial = (float*)(ws_pre + (size_t)N_EDGES * 64);  // 8192 f32
    float*    params       = stat_partial + STAT_SLOTS * 256;          // 256 f32
    ushort*   Wb           = (ushort*)(params + 256);                  // 24576 bf16
    unsigned* counts       = (unsigned*)(Wb + 2 * 64 * KDIM);          // 50000
    unsigned* row_start    = counts + N_ATOMS;                         // 50001
    unsigned* rank         = row_start + N_ATOMS + 1;                  // 800000

    const size_t need_full = (size_t)((char*)(rank + N_EDGES) - (char*)d_ws);
    const int full = (ws_size >= need_full) ? 1 : 0;

    setup_all<<<256, 256, 0, stream>>>(Wc, Wf, Wb, stat_partial, counts);

    if (full) {
        hist_rank<<<N_EDGES / 256, 256, 0, stream>>>(eidx, counts, rank);
        scan_one<<<1, SCAN_T, 0, stream>>>(counts, row_start);
        gemm_stats_store<<<GRID1, 256, 0, stream>>>(atom, edgef, Wb, eidx,
                                                    row_start, rank,
                                                    stat_partial, ws_pre, 1);
        finalize_stats<<<1, 128, 0, stream>>>(stat_partial, gc, btc, gf, btf, params);
        bn_act_reduce<<<N_ATOMS / 4, 256, 0, stream>>>(ws_pre, row_start,
                                                       atom, params, out);
    } else {
        gemm_stats_store<<<GRID1, 256, 0, stream>>>(atom, edgef, Wb, eidx,
                                                    (unsigned*)counts /*unused*/,
                                                    (unsigned*)counts /*unused*/,
                                                    stat_partial, ws_pre, 0);
        finalize_stats<<<1, 128, 0, stream>>>(stat_partial, gc, btc, gf, btf, params);
        copy_out<<<(N_ATOMS * 64 / 4) / 256, 256, 0, stream>>>(
            (const f32x4*)atom, (f32x4*)out);
        apply_scatter_fb<<<GRID1, 256, 0, stream>>>(atom, edgef, Wb, eidx,
                                                    params, out);
    }
}

// Round 8
// 482.126 us; speedup vs baseline: 1.2675x; 1.2675x over previous
//
#include <hip/hip_runtime.h>
#include <hip/hip_bf16.h>
#include <math.h>

// Problem constants
#define N_ATOMS   50000
#define N_EDGES   800000
#define KDIM      192
#define BN_EPS    1e-5f

#define TILE_E     64
#define TPB        10                      // tiles per block (pass 1)
#define NTILES     (N_EDGES / TILE_E)      // 12500
#define GRID1      (NTILES / TPB)          // 1250
#define STAT_SLOTS 32
#define ZSTRIDE    200   // bf16 elems per z row (192 + 8 pad, 16B-aligned rows)
#define NSCANBLK   ((N_ATOMS + 255) / 256) // 196

typedef __attribute__((ext_vector_type(8))) __bf16 bf16x8;
typedef __attribute__((ext_vector_type(4))) float  f32x4;
typedef __attribute__((ext_vector_type(4))) unsigned short u16x4;

__device__ __forceinline__ ushort f2bf(float f) {
    union { float f; unsigned u; } v; v.f = f;
    unsigned u = v.u;
    return (ushort)((u + 0x7FFFu + ((u >> 16) & 1u)) >> 16);
}
__device__ __forceinline__ float bf2f(unsigned hi16) {
    union { unsigned u; float f; } v; v.u = hi16 << 16; return v.f;
}
// BN + sigmoid*softplus message from packed (core | filter<<16) bf16 pair
__device__ __forceinline__ float msgf(unsigned pv, float sc_c, float sh_c,
                                      float sc_f, float sh_f) {
    float pc = fmaf(bf2f(pv & 0xFFFFu), sc_c, sh_c);
    float pf = fmaf(bf2f(pv >> 16),     sc_f, sh_f);
    float sp = fmaxf(pc, 0.f) + __logf(1.f + __expf(-fabsf(pc)));
    float sg = 1.f / (1.f + __expf(-pf));
    return sp * sg;
}

// ---------------------------------------------------------------------------
// Main-kernel gather: atom segments come from the PRE-CONVERTED bf16 table
// (8B/thread instead of 16B -> half the L2 gather bytes; commit needs NO
// conversion for them). Edge-feature segment stays f32 (streamed once).
// Same prefetch shape as round 0/6: ALL segments issued one tile ahead.
// ---------------------------------------------------------------------------
__device__ __forceinline__ void gather_issue_m(
    const ushort* __restrict__ atom_bf, const float* __restrict__ edgef,
    const int* __restrict__ eidx, int tilebase, int tid,
    u16x4* va, f32x4* ve)
{
    const int er = tid >> 4, f4 = tid & 15;
#pragma unroll
    for (int it = 0; it < 8; ++it) {
        const int seg = it >> 2;                 // 0=dst, 1=src
        const int e   = (it & 3) * 16 + er;
        const ushort* srcp =
            atom_bf + (size_t)eidx[2 * (tilebase + e) + (seg == 0 ? 1 : 0)] * 64;
        va[it] = *(const u16x4*)(srcp + f4 * 4);
    }
#pragma unroll
    for (int it = 0; it < 4; ++it) {
        const int e = it * 16 + er;
        ve[it] = *(const f32x4*)(edgef + (size_t)(tilebase + e) * 64 + f4 * 4);
    }
}

__device__ __forceinline__ void gather_commit_m(
    const u16x4* va, const f32x4* ve, ushort* zl, int tid)
{
    const int er = tid >> 4, f4 = tid & 15;
#pragma unroll
    for (int it = 0; it < 8; ++it) {             // atom segs: direct copy
        const int seg = it >> 2;
        const int e   = (it & 3) * 16 + er;
        *(u16x4*)&zl[e * ZSTRIDE + seg * 64 + f4 * 4] = va[it];
    }
#pragma unroll
    for (int it = 0; it < 4; ++it) {             // ef seg: convert
        const int e = it * 16 + er;
        u16x4 b;
        b.x = f2bf(ve[it].x); b.y = f2bf(ve[it].y);
        b.z = f2bf(ve[it].z); b.w = f2bf(ve[it].w);
        *(u16x4*)&zl[e * ZSTRIDE + 128 + f4 * 4] = b;
    }
}

// Full-z f32 gather helpers (fallback kernel only)
__device__ __forceinline__ void gather_issue(
    const float* __restrict__ atom, const float* __restrict__ edgef,
    const int* __restrict__ eidx, int tilebase, int tid, f32x4* v)
{
    const int er = tid >> 4, f4 = tid & 15;
#pragma unroll
    for (int it = 0; it < 12; ++it) {
        const int seg = it >> 2;
        const int e   = (it & 3) * 16 + er;
        const float* srcp;
        if (seg == 0)      srcp = atom  + (size_t)eidx[2 * (tilebase + e) + 1] * 64;
        else if (seg == 1) srcp = atom  + (size_t)eidx[2 * (tilebase + e)] * 64;
        else               srcp = edgef + (size_t)(tilebase + e) * 64;
        v[it] = *(const f32x4*)(srcp + f4 * 4);
    }
}

__device__ __forceinline__ void gather_commit(const f32x4* v, ushort* zl, int tid)
{
    const int er = tid >> 4, f4 = tid & 15;
#pragma unroll
    for (int it = 0; it < 12; ++it) {
        const int seg = it >> 2;
        const int e   = (it & 3) * 16 + er;
        u16x4 b;
        b.x = f2bf(v[it].x); b.y = f2bf(v[it].y);
        b.z = f2bf(v[it].z); b.w = f2bf(v[it].w);
        *(u16x4*)&zl[e * ZSTRIDE + seg * 64 + f4 * 4] = b;
    }
}

// ---------------------------------------------------------------------------
// Pass 1 (round-6 163-167us structure; TPB=10 to amortize the prologue):
// prefetch-double-buffered gather + MFMA dual-GEMM + column sum/sumsq.
// Inline perml build: perml[i] = row_start[dst(e)] + rank[e].
// Pre-act rows stored PERMUTED to CSR slots; bias dropped (cancels under BN).
// One __syncthreads per tile: commit(t) | sync | issue(t+1) | MFMA(t)+store.
// ---------------------------------------------------------------------------
__global__ __launch_bounds__(256) void gemm_stats_store(
    const ushort* __restrict__ atom_bf, const float* __restrict__ edgef,
    const ushort* __restrict__ Wb, const int* __restrict__ eidx,
    const unsigned* __restrict__ row_start, const unsigned* __restrict__ rank,
    float* __restrict__ stat_partial, unsigned* __restrict__ ws_pre,
    int do_store)
{
    __shared__ __align__(16) ushort zbuf[2][TILE_E * ZSTRIDE]; // 2x25.6KB
    __shared__ unsigned perml[TPB * TILE_E];                   // 2.5KB
    const int tid  = threadIdx.x;
    const int lane = tid & 63, wave = tid >> 6;
    const int ch = wave >> 1, rp = wave & 1;
    const int row = lane & 15, quad = lane >> 4;

    const int t0 = blockIdx.x * TPB;
    if (do_store) {
        for (int i = tid; i < TPB * TILE_E; i += 256) {
            const int e = t0 * TILE_E + i;
            const int d = eidx[2 * e + 1];
            perml[i] = row_start[d] + rank[e];
        }
    }

    bf16x8 bfr[2][2][6];
#pragma unroll
    for (int m = 0; m < 2; ++m)
#pragma unroll
        for (int nt = 0; nt < 2; ++nt)
#pragma unroll
            for (int ks = 0; ks < 6; ++ks)
                bfr[m][nt][ks] = *(const bf16x8*)&Wb[
                    (size_t)(m * 64 + ch * 32 + nt * 16 + row) * KDIM + ks * 32 + quad * 8];

    float s[2][2] = {{0.f, 0.f}, {0.f, 0.f}};
    float q[2][2] = {{0.f, 0.f}, {0.f, 0.f}};

    u16x4 pva[8];
    f32x4 pve[4];
    gather_issue_m(atom_bf, edgef, eidx, t0 * TILE_E, tid, pva, pve);

    for (int tt = 0; tt < TPB; ++tt) {
        ushort* zl = zbuf[tt & 1];
        gather_commit_m(pva, pve, zl, tid);
        __syncthreads();   // zl + perml visible; also protects buffer reuse
        if (tt + 1 < TPB)
            gather_issue_m(atom_bf, edgef, eidx, (t0 + tt + 1) * TILE_E, tid,
                           pva, pve);

#pragma unroll
        for (int ett = 0; ett < 2; ++ett) {
            const ushort* zb = zl + ((2 * rp + ett) * 16 + row) * ZSTRIDE;
            bf16x8 a[6];
#pragma unroll
            for (int ks = 0; ks < 6; ++ks)
                a[ks] = *(const bf16x8*)&zb[ks * 32 + quad * 8];
            f32x4 acc[2][2];
#pragma unroll
            for (int m = 0; m < 2; ++m)
#pragma unroll
                for (int nt = 0; nt < 2; ++nt)
                    acc[m][nt] = (f32x4){0.f, 0.f, 0.f, 0.f};
#pragma unroll
            for (int ks = 0; ks < 6; ++ks)
#pragma unroll
                for (int m = 0; m < 2; ++m)
#pragma unroll
                    for (int nt = 0; nt < 2; ++nt)
                        acc[m][nt] = __builtin_amdgcn_mfma_f32_16x16x32_bf16(
                            a[ks], bfr[m][nt][ks], acc[m][nt], 0, 0, 0);
#pragma unroll
            for (int nt = 0; nt < 2; ++nt) {
                const int c = ch * 32 + nt * 16 + row;
#pragma unroll
                for (int r = 0; r < 4; ++r) {
                    float vc = acc[0][nt][r], vf = acc[1][nt][r];
                    s[0][nt] += vc; q[0][nt] += vc * vc;
                    s[1][nt] += vf; q[1][nt] += vf * vf;
                    if (do_store) {
                        const int eloc = (2 * rp + ett) * 16 + quad * 4 + r;
                        const unsigned pos = perml[tt * TILE_E + eloc];
                        unsigned pack = (unsigned)f2bf(vc) | ((unsigned)f2bf(vf) << 16);
                        ws_pre[(size_t)pos * 64 + c] = pack;  // plain store: L2 merges
                    }
                }
            }
        }
    }

    float* slot = stat_partial + (size_t)(blockIdx.x & (STAT_SLOTS - 1)) * 256;
#pragma unroll
    for (int m = 0; m < 2; ++m)
#pragma unroll
        for (int nt = 0; nt < 2; ++nt) {
            float sv = s[m][nt], qv = q[m][nt];
            sv += __shfl_xor(sv, 16, 64); sv += __shfl_xor(sv, 32, 64);
            qv += __shfl_xor(qv, 16, 64); qv += __shfl_xor(qv, 32, 64);
            if (lane < 16) {
                int c = ch * 32 + nt * 16 + lane;
                atomicAdd(slot + m * 128 + c, sv);
                atomicAdd(slot + m * 128 + 64 + c, qv);
            }
        }
}

// ---------------------------------------------------------------------------
// Fused setup: zero stat_partial + counts, convert weights AND atom features
// to bf16 (atom_bf: the gather then reads half the bytes, commit skips f2bf;
// same f2bf rounding applied once here -> z bytes bit-identical).
// ---------------------------------------------------------------------------
__global__ __launch_bounds__(256) void setup_all(
    const float* __restrict__ Wc, const float* __restrict__ Wf,
    const float* __restrict__ atom,
    ushort* __restrict__ Wb, ushort* __restrict__ atom_bf,
    float* __restrict__ stat_partial, unsigned* __restrict__ counts)
{
    int i = blockIdx.x * 256 + threadIdx.x;       // 256 blocks -> 65536 threads
    if (i < 2 * 64 * KDIM) {
        float v = (i < 64 * KDIM) ? Wc[i] : Wf[i - 64 * KDIM];
        Wb[i] = f2bf(v);
    }
    if (i < STAT_SLOTS * 256) stat_partial[i] = 0.f;
    if (i < N_ATOMS) counts[i] = 0u;
    // atom f32 -> bf16, vectorized x4, grid-stride (800k f32x4 chunks)
    for (int j = i; j < N_ATOMS * 64 / 4; j += 256 * 256) {
        f32x4 v = ((const f32x4*)atom)[j];
        u16x4 b;
        b.x = f2bf(v.x); b.y = f2bf(v.y); b.z = f2bf(v.z); b.w = f2bf(v.w);
        ((u16x4*)atom_bf)[j] = b;
    }
}

// ---------------------------------------------------------------------------
// Fold BN into per-column scale/shift (1-block kernel).
// params: [0..63]=scale_c [64..127]=scale_f [128..191]=shift_c [192..255]=shift_f
// ---------------------------------------------------------------------------
__global__ void finalize_stats(const float* __restrict__ stat_partial,
                               const float* __restrict__ gc, const float* __restrict__ btc,
                               const float* __restrict__ gf, const float* __restrict__ btf,
                               float* __restrict__ params)
{
    int t = threadIdx.x;            // 0..127
    bool isf = t >= 64;
    int j = t & 63;
    float s = 0.f, q = 0.f;
    for (int slot = 0; slot < STAT_SLOTS; slot++) {
        const float* sp = stat_partial + (size_t)slot * 256 + (isf ? 128 : 0);
        s += sp[j];
        q += sp[64 + j];
    }
    float mean = s / (float)N_EDGES;
    float var  = q / (float)N_EDGES - mean * mean;
    float inv  = rsqrtf(var + BN_EPS);
    float gamma = isf ? gf[j] : gc[j];
    float beta  = isf ? btf[j] : btc[j];
    float scale = gamma * inv;
    float shift = beta - mean * scale;
    params[t]       = scale;
    params[128 + t] = shift;
}

// ---------------------------------------------------------------------------
// CSR-slot assignment (round-6 proven chain):
//   hist_rank: rank[e] = atomicAdd(&counts[d],1)  (the histogram atomic's
//              return value IS the within-dst rank); int2 load (coalesced).
//   scan_a/scan_b: 2-level exclusive scan; init_row globalizes (+sentinel).
// ---------------------------------------------------------------------------
__global__ __launch_bounds__(256) void hist_rank(const int* __restrict__ eidx,
                                                 unsigned* __restrict__ counts,
                                                 unsigned* __restrict__ rank)
{
    int e = blockIdx.x * 256 + threadIdx.x;          // 3125 blocks
    int2 p = ((const int2*)eidx)[e];
    rank[e] = atomicAdd(&counts[p.y], 1u);
}

__global__ __launch_bounds__(256) void scan_a(const unsigned* __restrict__ counts,
                                              unsigned* __restrict__ row_start,
                                              unsigned* __restrict__ blksum)
{
    __shared__ unsigned sh[256];
    const int tid = threadIdx.x;
    const int i = blockIdx.x * 256 + tid;
    unsigned v = (i < N_ATOMS) ? counts[i] : 0u;
    sh[tid] = v;
    __syncthreads();
    for (int off = 1; off < 256; off <<= 1) {
        unsigned t = (tid >= off) ? sh[tid - off] : 0u;
        __syncthreads();
        sh[tid] += t;
        __syncthreads();
    }
    if (i < N_ATOMS) row_start[i] = sh[tid] - v;     // exclusive (block-local)
    if (tid == 255) blksum[blockIdx.x] = sh[tid];
}

__global__ void scan_b(unsigned* __restrict__ blksum)   // 1 block
{
    __shared__ unsigned sh[256];
    const int tid = threadIdx.x;
    unsigned v = (tid < NSCANBLK) ? blksum[tid] : 0u;
    sh[tid] = v;
    __syncthreads();
    for (int off = 1; off < 256; off <<= 1) {
        unsigned t = (tid >= off) ? sh[tid - off] : 0u;
        __syncthreads();
        sh[tid] += t;
        __syncthreads();
    }
    if (tid < NSCANBLK) blksum[tid] = sh[tid] - v;   // exclusive
}

__global__ __launch_bounds__(256) void init_row(unsigned* __restrict__ row_start,
                                                const unsigned* __restrict__ blksum)
{
    int i = blockIdx.x * 256 + threadIdx.x;
    if (i < N_ATOMS) row_start[i] += blksum[i >> 8];  // globalize
    if (i == 0) row_start[N_ATOMS] = N_EDGES;         // sentinel
}

// ---------------------------------------------------------------------------
// Pass 3: streaming gather-reduce (round-6 form). ws_pre rows are in CSR
// order: each wave (one atom, lane = column) reads a CONTIGUOUS run of 256B
// rows. One plain store per atom; no atomics, no index indirection.
// ---------------------------------------------------------------------------
__global__ __launch_bounds__(256) void bn_act_reduce(
    const unsigned* __restrict__ ws_pre, const unsigned* __restrict__ row_start,
    const float* __restrict__ atom, const float* __restrict__ params,
    float* __restrict__ out)
{
    const int lane = threadIdx.x & 63;
    const int a    = blockIdx.x * 4 + (threadIdx.x >> 6);

    const float sc_c = params[lane],      sh_c = params[128 + lane];
    const float sc_f = params[64 + lane], sh_f = params[192 + lane];

    const unsigned jb = row_start[a];
    const unsigned n  = row_start[a + 1] - jb;
    const unsigned* base = ws_pre + (size_t)jb * 64 + lane;

    float acc = 0.f;
    unsigned k = 0;
    for (; k + 8 <= n; k += 8) {
        unsigned p[8];
#pragma unroll
        for (int u = 0; u < 8; ++u) p[u] = base[(size_t)(k + u) * 64];
#pragma unroll
        for (int u = 0; u < 8; ++u) acc += msgf(p[u], sc_c, sh_c, sc_f, sh_f);
    }
    for (; k < n; ++k) acc += msgf(base[(size_t)k * 64], sc_c, sh_c, sc_f, sh_f);

    out[(size_t)a * 64 + lane] = atom[(size_t)a * 64 + lane] + acc;
}

// ---------------------------------------------------------------------------
// Fallback path (ws too small): recompute GEMM + atomic scatter (no ws_pre,
// no atom_bf -- uses original f32 inputs).
// ---------------------------------------------------------------------------
__global__ __launch_bounds__(256) void copy_out(const f32x4* __restrict__ src,
                                                f32x4* __restrict__ dst)
{
    int i = blockIdx.x * blockDim.x + threadIdx.x;
    dst[i] = src[i];
}

__global__ __launch_bounds__(256) void convert_weights_fb(
    const float* __restrict__ Wc, const float* __restrict__ Wf,
    ushort* __restrict__ Wb, float* __restrict__ stat_partial)
{
    int i = blockIdx.x * 256 + threadIdx.x;
    if (i < 2 * 64 * KDIM) {
        float v = (i < 64 * KDIM) ? Wc[i] : Wf[i - 64 * KDIM];
        Wb[i] = f2bf(v);
    }
    if (i < STAT_SLOTS * 256) stat_partial[i] = 0.f;
}

#define TPB_FB 5
__global__ __launch_bounds__(256) void gemm_stats_fb(
    const float* __restrict__ atom, const float* __restrict__ edgef,
    const ushort* __restrict__ Wb, const int* __restrict__ eidx,
    float* __restrict__ stat_partial)
{
    __shared__ __align__(16) ushort zl[TILE_E * ZSTRIDE];
    const int tid  = threadIdx.x;
    const int lane = tid & 63, wave = tid >> 6;
    const int ch = wave >> 1, rp = wave & 1;
    const int row = lane & 15, quad = lane >> 4;

    bf16x8 bfr[2][2][6];
#pragma unroll
    for (int m = 0; m < 2; ++m)
#pragma unroll
        for (int nt = 0; nt < 2; ++nt)
#pragma unroll
            for (int ks = 0; ks < 6; ++ks)
                bfr[m][nt][ks] = *(const bf16x8*)&Wb[
                    (size_t)(m * 64 + ch * 32 + nt * 16 + row) * KDIM + ks * 32 + quad * 8];

    float s[2][2] = {{0.f, 0.f}, {0.f, 0.f}};
    float q[2][2] = {{0.f, 0.f}, {0.f, 0.f}};

    const int t0 = blockIdx.x * TPB_FB;
    for (int tt = 0; tt < TPB_FB; ++tt) {
        const int tilebase = (t0 + tt) * TILE_E;
        f32x4 pre[12];
        gather_issue(atom, edgef, eidx, tilebase, tid, pre);
        __syncthreads();
        gather_commit(pre, zl, tid);
        __syncthreads();
#pragma unroll
        for (int ett = 0; ett < 2; ++ett) {
            const ushort* zb = zl + ((2 * rp + ett) * 16 + row) * ZSTRIDE;
            bf16x8 a[6];
#pragma unroll
            for (int ks = 0; ks < 6; ++ks)
                a[ks] = *(const bf16x8*)&zb[ks * 32 + quad * 8];
            f32x4 acc[2][2];
#pragma unroll
            for (int m = 0; m < 2; ++m)
#pragma unroll
                for (int nt = 0; nt < 2; ++nt)
                    acc[m][nt] = (f32x4){0.f, 0.f, 0.f, 0.f};
#pragma unroll
            for (int ks = 0; ks < 6; ++ks)
#pragma unroll
                for (int m = 0; m < 2; ++m)
#pragma unroll
                    for (int nt = 0; nt < 2; ++nt)
                        acc[m][nt] = __builtin_amdgcn_mfma_f32_16x16x32_bf16(
                            a[ks], bfr[m][nt][ks], acc[m][nt], 0, 0, 0);
#pragma unroll
            for (int nt = 0; nt < 2; ++nt) {
#pragma unroll
                for (int r = 0; r < 4; ++r) {
                    float vc = acc[0][nt][r], vf = acc[1][nt][r];
                    s[0][nt] += vc; q[0][nt] += vc * vc;
                    s[1][nt] += vf; q[1][nt] += vf * vf;
                }
            }
        }
    }

    float* slot = stat_partial + (size_t)(blockIdx.x & (STAT_SLOTS - 1)) * 256;
#pragma unroll
    for (int m = 0; m < 2; ++m)
#pragma unroll
        for (int nt = 0; nt < 2; ++nt) {
            float sv = s[m][nt], qv = q[m][nt];
            sv += __shfl_xor(sv, 16, 64); sv += __shfl_xor(sv, 32, 64);
            qv += __shfl_xor(qv, 16, 64); qv += __shfl_xor(qv, 32, 64);
            if (lane < 16) {
                int c = ch * 32 + nt * 16 + lane;
                atomicAdd(slot + m * 128 + c, sv);
                atomicAdd(slot + m * 128 + 64 + c, qv);
            }
        }
}

__global__ __launch_bounds__(256) void apply_scatter_fb(
    const float* __restrict__ atom, const float* __restrict__ edgef,
    const ushort* __restrict__ Wb, const int* __restrict__ eidx,
    const float* __restrict__ params, float* __restrict__ out)
{
    __shared__ __align__(16) ushort zl[TILE_E * ZSTRIDE];
    const int tid  = threadIdx.x;
    const int lane = tid & 63, wave = tid >> 6;
    const int ch = wave >> 1, rp = wave & 1;
    const int row = lane & 15, quad = lane >> 4;

    bf16x8 bfr[2][2][6];
#pragma unroll
    for (int m = 0; m < 2; ++m)
#pragma unroll
        for (int nt = 0; nt < 2; ++nt)
#pragma unroll
            for (int ks = 0; ks < 6; ++ks)
                bfr[m][nt][ks] = *(const bf16x8*)&Wb[
                    (size_t)(m * 64 + ch * 32 + nt * 16 + row) * KDIM + ks * 32 + quad * 8];

    float scc[2], shc[2], scf[2], shf[2];
#pragma unroll
    for (int nt = 0; nt < 2; ++nt) {
        int c = ch * 32 + nt * 16 + row;
        scc[nt] = params[c];        shc[nt] = params[128 + c];
        scf[nt] = params[64 + c];   shf[nt] = params[192 + c];
    }

    const int t0 = blockIdx.x * TPB_FB;
    for (int tt = 0; tt < TPB_FB; ++tt) {
        const int tilebase = (t0 + tt) * TILE_E;
        f32x4 pre[12];
        gather_issue(atom, edgef, eidx, tilebase, tid, pre);
        __syncthreads();
        gather_commit(pre, zl, tid);
        __syncthreads();
#pragma unroll
        for (int ett = 0; ett < 2; ++ett) {
            const ushort* zb = zl + ((2 * rp + ett) * 16 + row) * ZSTRIDE;
            bf16x8 a[6];
#pragma unroll
            for (int ks = 0; ks < 6; ++ks)
                a[ks] = *(const bf16x8*)&zb[ks * 32 + quad * 8];
            f32x4 acc[2][2];
#pragma unroll
            for (int m = 0; m < 2; ++m)
#pragma unroll
                for (int nt = 0; nt < 2; ++nt)
                    acc[m][nt] = (f32x4){0.f, 0.f, 0.f, 0.f};
#pragma unroll
            for (int ks = 0; ks < 6; ++ks)
#pragma unroll
                for (int m = 0; m < 2; ++m)
#pragma unroll
                    for (int nt = 0; nt < 2; ++nt)
                        acc[m][nt] = __builtin_amdgcn_mfma_f32_16x16x32_bf16(
                            a[ks], bfr[m][nt][ks], acc[m][nt], 0, 0, 0);
#pragma unroll
            for (int nt = 0; nt < 2; ++nt) {
                int c = ch * 32 + nt * 16 + row;
#pragma unroll
                for (int r = 0; r < 4; ++r) {
                    float pc = fmaf(acc[0][nt][r], scc[nt], shc[nt]);
                    float pf = fmaf(acc[1][nt][r], scf[nt], shf[nt]);
                    float sp = fmaxf(pc, 0.f) + __logf(1.f + __expf(-fabsf(pc)));
                    float sg = 1.f / (1.f + __expf(-pf));
                    int eloc = (2 * rp + ett) * 16 + quad * 4 + r;
                    int d = eidx[2 * (tilebase + eloc) + 1];
                    atomicAdd(out + (size_t)d * 64 + c, sp * sg);
                }
            }
        }
    }
}

// ---------------------------------------------------------------------------
extern "C" void kernel_launch(void* const* d_in, const int* in_sizes, int n_in,
                              void* d_out, int out_size, void* d_ws, size_t ws_size,
                              hipStream_t stream)
{
    const float* atom  = (const float*)d_in[0];
    const float* edgef = (const float*)d_in[1];
    const float* Wf    = (const float*)d_in[2];
    const float* gf    = (const float*)d_in[4];
    const float* btf   = (const float*)d_in[5];
    const float* Wc    = (const float*)d_in[6];
    const float* gc    = (const float*)d_in[8];
    const float* btc   = (const float*)d_in[9];
    const int*   eidx  = (const int*)d_in[10];
    float* out = (float*)d_out;

    // workspace layout (ws_pre first keeps everything 16B-aligned; row_start
    // padded to even count so atom_bf stays 8B-aligned)
    unsigned* ws_pre       = (unsigned*)d_ws;                          // N_EDGES*64
    float*    stat_partial = (float*)(ws_pre + (size_t)N_EDGES * 64);  // 8192 f32
    float*    params       = stat_partial + STAT_SLOTS * 256;          // 256 f32
    ushort*   Wb           = (ushort*)(params + 256);                  // 24576 bf16
    unsigned* counts       = (unsigned*)(Wb + 2 * 64 * KDIM);          // 50000
    unsigned* row_start    = counts + N_ATOMS;                         // 50002 (pad)
    unsigned* rank         = row_start + N_ATOMS + 2;                  // 800000
    ushort*   atom_bf      = (ushort*)(rank + N_EDGES);                // 3.2M bf16
    unsigned* blksum       = (unsigned*)(atom_bf + (size_t)N_ATOMS * 64); // 256

    const size_t need_full = (size_t)((char*)(blksum + 256) - (char*)d_ws);
    const int full = (ws_size >= need_full) ? 1 : 0;

    if (full) {
        setup_all<<<256, 256, 0, stream>>>(Wc, Wf, atom, Wb, atom_bf,
                                           stat_partial, counts);
        hist_rank<<<N_EDGES / 256, 256, 0, stream>>>(eidx, counts, rank);
        scan_a<<<NSCANBLK, 256, 0, stream>>>(counts, row_start, blksum);
        scan_b<<<1, 256, 0, stream>>>(blksum);
        init_row<<<NSCANBLK, 256, 0, stream>>>(row_start, blksum);
        gemm_stats_store<<<GRID1, 256, 0, stream>>>(atom_bf, edgef, Wb, eidx,
                                                    row_start, rank,
                                                    stat_partial, ws_pre, 1);
        finalize_stats<<<1, 128, 0, stream>>>(stat_partial, gc, btc, gf, btf, params);
        bn_act_reduce<<<N_ATOMS / 4, 256, 0, stream>>>(ws_pre, row_start,
                                                       atom, params, out);
    } else {
        convert_weights_fb<<<256, 256, 0, stream>>>(Wc, Wf, Wb, stat_partial);
        gemm_stats_fb<<<NTILES / TPB_FB, 256, 0, stream>>>(atom, edgef, Wb, eidx,
                                                           stat_partial);
        finalize_stats<<<1, 128, 0, stream>>>(stat_partial, gc, btc, gf, btf, params);
        copy_out<<<(N_ATOMS * 64 / 4) / 256, 256, 0, stream>>>(
            (const f32x4*)atom, (f32x4*)out);
        apply_scatter_fb<<<NTILES / TPB_FB, 256, 0, stream>>>(atom, edgef, Wb, eidx,
                                                              params, out);
    }
}